// Round 7
// baseline (1441.183 us; speedup 1.0000x reference)
//
#include <hip/hip_runtime.h>
#include <math.h>

#define B_   32
#define L_   4096
#define IN_  1024
#define QS_  64
#define VS_  256
#define H_   16

#define Q_OFF   0
#define M_OFF   32768

__device__ __forceinline__ float dot4(float4 a, float4 b) {
    return a.x*b.x + a.y*b.y + a.z*b.z + a.w*b.w;
}

// ---------------------------------------------------------------------------
// Kernel A: q[b,c] = (query[b,:] . Wq[c,:] + bq[c]) / 8
// ---------------------------------------------------------------------------
__global__ __launch_bounds__(256) void qproj_kernel(
        const float* __restrict__ query, const float* __restrict__ Wq,
        const float* __restrict__ bq, float* __restrict__ ws) {
    const int t = threadIdx.x;
    const int lm = t & 63, w = t >> 6;
    const int o = blockIdx.x * 4 + w;
    const int b = o >> 10, c = o & 1023;

    const float4* wq4 = (const float4*)(Wq + (size_t)c * IN_);
    const float4* q4  = (const float4*)(query + (size_t)b * IN_);
    float4 acc = make_float4(0.f, 0.f, 0.f, 0.f);
    #pragma unroll
    for (int j = 0; j < 4; ++j) {
        float4 wv = wq4[j * 64 + lm];
        float4 qv = q4[j * 64 + lm];
        acc.x += wv.x * qv.x; acc.y += wv.y * qv.y;
        acc.z += wv.z * qv.z; acc.w += wv.w * qv.w;
    }
    float r = acc.x + acc.y + acc.z + acc.w;
    #pragma unroll
    for (int off = 32; off >= 1; off >>= 1) r += __shfl_xor(r, off);
    if (lm == 0) ws[Q_OFF + b * 1024 + c] = (r + bq[c]) * 0.125f;
}

// ---------------------------------------------------------------------------
// Kernel B: per (b, chunk of CL rows). 4 waves, wave w owns heads 4w..4w+3.
// Phase B: 4-deep global_load_lds pipeline, counted vmcnt, raw s_barrier.
// ---------------------------------------------------------------------------
template<int CL>
__global__ __launch_bounds__(256, 4) void attn_chunk_kernel(
        const float* __restrict__ key, const float* __restrict__ value,
        float* __restrict__ ws) {
    constexpr int NCH = L_ / CL;
    constexpr int R   = CL / 64;          // rows per lane in phase A
    constexpr int NT  = CL / 8;           // 8-row tiles in phase B
    constexpr int S_OFFc   = M_OFF + B_ * NCH * H_;
    constexpr int CTX_OFFc = S_OFFc + B_ * NCH * H_;

    __shared__ float4 qs4[256];                        // 4 KB
    __shared__ float4 ps4[4 * CL];                     // 4/8 KB
    __shared__ __align__(16) float vbuf[4][8][VS_];    // 32 KB

    const int t  = threadIdx.x;
    const int ch = blockIdx.x, b = blockIdx.y;
    const int lm = t & 63, w = t >> 6;
    const int l0 = ch * CL;

    qs4[t] = ((const float4*)(ws + Q_OFF + (size_t)b * IN_))[t];
    __syncthreads();

    // ---- Phase A: lane owns rows j*64+lm; wave's 4 heads. 8-deep key loads.
    const float* keyb = key + ((size_t)b * L_ + l0) * QS_;
    float s[R][4];
    #pragma unroll
    for (int j = 0; j < R; ++j)
        #pragma unroll
        for (int hh = 0; hh < 4; ++hh) s[j][hh] = 0.f;

    #pragma unroll
    for (int j = 0; j < R; ++j) {
        const float4* krow = (const float4*)(keyb + (size_t)(j * 64 + lm) * QS_);
        #pragma unroll
        for (int half = 0; half < 2; ++half) {
            float4 kv[8];
            #pragma unroll
            for (int e = 0; e < 8; ++e) kv[e] = krow[half * 8 + e];
            #pragma unroll
            for (int e = 0; e < 8; ++e) {
                #pragma unroll
                for (int hh = 0; hh < 4; ++hh)
                    s[j][hh] += dot4(kv[e], qs4[(4 * w + hh) * 16 + half * 8 + e]);
            }
        }
    }

    // wave-local softmax stats (rows live across lanes and j)
    float m[4], sum[4], p[R][4];
    #pragma unroll
    for (int hh = 0; hh < 4; ++hh) {
        float v = s[0][hh];
        #pragma unroll
        for (int j = 1; j < R; ++j) v = fmaxf(v, s[j][hh]);
        #pragma unroll
        for (int off = 32; off >= 1; off >>= 1) v = fmaxf(v, __shfl_xor(v, off));
        m[hh] = v;
    }
    #pragma unroll
    for (int j = 0; j < R; ++j)
        #pragma unroll
        for (int hh = 0; hh < 4; ++hh) p[j][hh] = __expf(s[j][hh] - m[hh]);
    #pragma unroll
    for (int hh = 0; hh < 4; ++hh) {
        float v = p[0][hh];
        #pragma unroll
        for (int j = 1; j < R; ++j) v += p[j][hh];
        #pragma unroll
        for (int off = 32; off >= 1; off >>= 1) v += __shfl_xor(v, off);
        sum[hh] = v;
    }

    // stash p: ps4[w*CL + row]  (wave-local; same-wave lgkm ordering)
    #pragma unroll
    for (int j = 0; j < R; ++j)
        ps4[w * CL + j * 64 + lm] = make_float4(p[j][0], p[j][1], p[j][2], p[j][3]);

    // ---- Phase B: 4-deep async pipeline. Tile = 8 rows = 8 KB.
    const float* valb = value + ((size_t)b * L_ + l0) * VS_;
    float4 ctx0 = make_float4(0.f,0.f,0.f,0.f), ctx1 = ctx0, ctx2 = ctx0, ctx3 = ctx0;

    #define ISSUE(tt) {                                                        \
        const float* g0 = valb + (size_t)(tt) * 2048 + t * 4;                  \
        float* l0p = &vbuf[(tt) & 3][0][0] + t * 4;                            \
        __builtin_amdgcn_global_load_lds(                                      \
            (const __attribute__((address_space(1))) void*)g0,                 \
            (__attribute__((address_space(3))) void*)l0p, 16, 0, 0);           \
        __builtin_amdgcn_global_load_lds(                                      \
            (const __attribute__((address_space(1))) void*)(g0 + 1024),        \
            (__attribute__((address_space(3))) void*)(l0p + 1024), 16, 0, 0);  \
    }

    #define CONSUME(tt) {                                                      \
        const int cb_ = (tt) & 3;                                              \
        _Pragma("unroll")                                                      \
        for (int rr = 0; rr < 8; ++rr) {                                       \
            float4 vv = *(const float4*)&vbuf[cb_][rr][4 * lm];                \
            float4 pu = ps4[w * CL + (tt) * 8 + rr];                           \
            ctx0.x += pu.x * vv.x; ctx0.y += pu.x * vv.y;                      \
            ctx0.z += pu.x * vv.z; ctx0.w += pu.x * vv.w;                      \
            ctx1.x += pu.y * vv.x; ctx1.y += pu.y * vv.y;                      \
            ctx1.z += pu.y * vv.z; ctx1.w += pu.y * vv.w;                      \
            ctx2.x += pu.z * vv.x; ctx2.y += pu.z * vv.y;                      \
            ctx2.z += pu.z * vv.z; ctx2.w += pu.z * vv.w;                      \
            ctx3.x += pu.w * vv.x; ctx3.y += pu.w * vv.y;                      \
            ctx3.z += pu.w * vv.z; ctx3.w += pu.w * vv.w;                      \
        }                                                                      \
    }

    asm volatile("s_waitcnt vmcnt(0)" ::: "memory");   // clean slate
    ISSUE(0) ISSUE(1) ISSUE(2) ISSUE(3)

    for (int tt = 0; tt < NT - 4; ++tt) {
        asm volatile("s_waitcnt vmcnt(6)" ::: "memory");   // tile tt landed (own wave)
        __builtin_amdgcn_s_barrier();                       // all waves' pieces landed
        asm volatile("" ::: "memory");
        CONSUME(tt)
        __builtin_amdgcn_s_barrier();                       // buffer free everywhere
        asm volatile("" ::: "memory");
        ISSUE(tt + 4)
    }
    asm volatile("s_waitcnt vmcnt(6)" ::: "memory");
    __builtin_amdgcn_s_barrier();
    asm volatile("" ::: "memory");
    CONSUME(NT - 4)
    asm volatile("s_waitcnt vmcnt(4)" ::: "memory");
    __builtin_amdgcn_s_barrier();
    asm volatile("" ::: "memory");
    CONSUME(NT - 3)
    asm volatile("s_waitcnt vmcnt(2)" ::: "memory");
    __builtin_amdgcn_s_barrier();
    asm volatile("" ::: "memory");
    CONSUME(NT - 2)
    asm volatile("s_waitcnt vmcnt(0)" ::: "memory");
    __builtin_amdgcn_s_barrier();
    asm volatile("" ::: "memory");
    CONSUME(NT - 1)
    #undef ISSUE
    #undef CONSUME

    // deferred stats + ctx write
    if (lm == 0) {
        #pragma unroll
        for (int hh = 0; hh < 4; ++hh) {
            ws[M_OFF  + (b * NCH + ch) * H_ + 4 * w + hh] = m[hh];
            ws[S_OFFc + (b * NCH + ch) * H_ + 4 * w + hh] = sum[hh];
        }
    }
    float* ctxw = ws + CTX_OFFc + (size_t)((b * NCH + ch) * H_) * VS_;
    *(float4*)(ctxw + (size_t)(4 * w + 0) * VS_ + 4 * lm) = ctx0;
    *(float4*)(ctxw + (size_t)(4 * w + 1) * VS_ + 4 * lm) = ctx1;
    *(float4*)(ctxw + (size_t)(4 * w + 2) * VS_ + 4 * lm) = ctx2;
    *(float4*)(ctxw + (size_t)(4 * w + 3) * VS_ + 4 * lm) = ctx3;
}

// ---------------------------------------------------------------------------
// Kernel C: flash-combine chunk partials + project. 512 thr: two chunk-halves
// in parallel, then 8-thread-per-output projection.
// ---------------------------------------------------------------------------
template<int NCH>
__global__ __launch_bounds__(512) void reduce_proj_kernel(
        const float* __restrict__ Wv, const float* __restrict__ bv,
        const float* __restrict__ ws, float* __restrict__ out) {
    constexpr int S_OFFc   = M_OFF + B_ * NCH * H_;
    constexpr int CTX_OFFc = S_OFFc + B_ * NCH * H_;
    constexpr int HALF = NCH / 2;

    __shared__ float m_l[NCH], s_l[NCH];
    __shared__ float accb[2][VS_];
    __shared__ float Sb[2];
    __shared__ __align__(16) float ctx_lds[VS_];

    const int t = threadIdx.x;
    const int e = t & 255, g = t >> 8;
    const int b = blockIdx.x >> 4, h = blockIdx.x & 15;

    if (t < NCH) m_l[t] = ws[M_OFF + (b * NCH + t) * H_ + h];
    else if (t < 2 * NCH) s_l[t - NCH] = ws[S_OFFc + (b * NCH + (t - NCH)) * H_ + h];
    __syncthreads();

    float M = -1e30f;
    #pragma unroll
    for (int c = 0; c < NCH; ++c) M = fmaxf(M, m_l[c]);

    float Sp = 0.f, acc = 0.f;
    #pragma unroll 8
    for (int c = g * HALF; c < (g + 1) * HALF; ++c) {
        float wgt = __expf(m_l[c] - M);
        Sp  += s_l[c] * wgt;
        acc += wgt * ws[CTX_OFFc + ((size_t)(b * NCH + c) * H_ + h) * VS_ + e];
    }
    accb[g][e] = acc;
    if (e == 0) Sb[g] = Sp;
    __syncthreads();

    if (g == 0)
        ctx_lds[e] = (accb[0][e] + accb[1][e]) / (Sb[0] + Sb[1]);
    __syncthreads();

    const int d = t >> 3, qq = t & 7;                 // 64 outputs x 8 threads
    const float4* wv4 = (const float4*)(Wv + (size_t)(h * 64 + d) * VS_);
    const float4* cl4 = (const float4*)ctx_lds;
    float a = 0.f;
    #pragma unroll
    for (int i = 0; i < 8; ++i) a += dot4(wv4[qq * 8 + i], cl4[qq * 8 + i]);
    a += __shfl_xor(a, 1);
    a += __shfl_xor(a, 2);
    a += __shfl_xor(a, 4);
    if (qq == 0) out[b * 1024 + h * 64 + d] = a + bv[h * 64 + d];
}

extern "C" void kernel_launch(void* const* d_in, const int* in_sizes, int n_in,
                              void* d_out, int out_size, void* d_ws, size_t ws_size,
                              hipStream_t stream) {
    (void)in_sizes; (void)n_in; (void)out_size;
    const float* query = (const float*)d_in[0];
    const float* key   = (const float*)d_in[1];
    const float* value = (const float*)d_in[2];
    const float* Wq    = (const float*)d_in[3];
    const float* bq    = (const float*)d_in[4];
    const float* Wv    = (const float*)d_in[5];
    const float* bv    = (const float*)d_in[6];
    float* out = (float*)d_out;
    float* ws  = (float*)d_ws;

    qproj_kernel<<<8192, 256, 0, stream>>>(query, Wq, bq, ws);

    // CL=64 path needs (32768 + 2*32*64*16 + 32*64*16*256) * 4 B  ~= 34 MB
    const size_t need64 = (size_t)(32768 + 2 * B_ * 64 * H_ + (size_t)B_ * 64 * H_ * VS_) * 4;
    if (ws_size >= need64) {
        attn_chunk_kernel<64><<<dim3(64, B_), 256, 0, stream>>>(key, value, ws);
        reduce_proj_kernel<64><<<B_ * H_, 512, 0, stream>>>(Wv, bv, ws, out);
    } else {
        attn_chunk_kernel<128><<<dim3(32, B_), 256, 0, stream>>>(key, value, ws);
        reduce_proj_kernel<32><<<B_ * H_, 512, 0, stream>>>(Wv, bv, ws, out);
    }
}